// Round 11
// baseline (128.476 us; speedup 1.0000x reference)
//
#include <hip/hip_runtime.h>
#include <math.h>

#define B_ROWS 8192
#define NU 512
#define FEATS 64
#define RPB 8
#define TOPK_K 8

typedef unsigned long long ull;

// ---------- u32 sort primitives (kernel 1) ----------
__device__ __forceinline__ void ce32(unsigned& a, unsigned& b, bool asc) {
  const unsigned mn = a < b ? a : b;
  const unsigned mx = a < b ? b : a;
  a = asc ? mn : mx;
  b = asc ? mx : mn;
}

template <unsigned M, unsigned KB>
__device__ __forceinline__ void cross32(unsigned v[8], unsigned lane, int addr) {
  const bool asc = ((lane & KB) == 0u);
  const bool takeMin = (((lane & M) == 0u) == asc);
#pragma unroll
  for (int i = 0; i < 8; ++i) {
    unsigned o;
    if constexpr (M == 1)
      o = (unsigned)__builtin_amdgcn_update_dpp((int)v[i], (int)v[i], 0xB1, 0xf, 0xf, true);
    else if constexpr (M == 2)
      o = (unsigned)__builtin_amdgcn_update_dpp((int)v[i], (int)v[i], 0x4E, 0xf, 0xf, true);
    else
      o = (unsigned)__builtin_amdgcn_ds_bpermute(addr, (int)v[i]);
    const unsigned mn = v[i] < o ? v[i] : o;
    const unsigned mx = v[i] < o ? o : v[i];
    v[i] = takeMin ? mn : mx;
  }
}

template <unsigned K>
__device__ __forceinline__ void stage32(unsigned v[8], unsigned lane,
                                        int a4, int a8, int a16, int a32) {
  constexpr unsigned KB = (K >> 3);
  if constexpr (K >= 512) cross32<32, KB>(v, lane, a32);
  if constexpr (K >= 256) cross32<16, KB>(v, lane, a16);
  if constexpr (K >= 128) cross32<8,  KB>(v, lane, a8);
  if constexpr (K >= 64)  cross32<4,  KB>(v, lane, a4);
  if constexpr (K >= 32)  cross32<2,  KB>(v, lane, 0);
  cross32<1, KB>(v, lane, 0);
  const bool asc = ((lane & KB) == 0u);
  ce32(v[0], v[4], asc); ce32(v[1], v[5], asc); ce32(v[2], v[6], asc); ce32(v[3], v[7], asc);
  ce32(v[0], v[2], asc); ce32(v[1], v[3], asc); ce32(v[4], v[6], asc); ce32(v[5], v[7], asc);
  ce32(v[0], v[1], asc); ce32(v[2], v[3], asc); ce32(v[4], v[5], asc); ce32(v[6], v[7], asc);
}

// ---------- u64 exact primitives (fix kernel, round-6-verified) ----------
__device__ __forceinline__ ull shfl_xor_u64(ull x, int m) {
  int lo = (int)(unsigned)(x & 0xffffffffULL);
  int hi = (int)(unsigned)(x >> 32);
  lo = __shfl_xor(lo, m, 64);
  hi = __shfl_xor(hi, m, 64);
  return ((ull)(unsigned)hi << 32) | (ull)(unsigned)lo;
}

template <int S>
__device__ __forceinline__ void inreg_pass(ull v[8], unsigned lane, unsigned k) {
#pragma unroll
  for (int i = 0; i < 8; ++i) {
    if ((i & S) == 0) {
      const int ip = i | S;
      const unsigned e = (lane << 3) | (unsigned)i;
      const bool asc = ((e & k) == 0);
      const ull a = v[i], b = v[ip];
      const bool lt = a < b;
      const ull lo2 = lt ? a : b;
      const ull hi2 = lt ? b : a;
      v[i]  = asc ? lo2 : hi2;
      v[ip] = asc ? hi2 : lo2;
    }
  }
}

__device__ __forceinline__ void cross_pass(ull v[8], unsigned lane, unsigned m, unsigned k) {
#pragma unroll
  for (int i = 0; i < 8; ++i) {
    const ull o = shfl_xor_u64(v[i], (int)m);
    const unsigned e = (lane << 3) | (unsigned)i;
    const bool takeMin = (((lane & m) == 0) == ((e & k) == 0));
    const bool keep = ((v[i] < o) == takeMin);
    v[i] = keep ? v[i] : o;
  }
}

// ============ kernel 1: distances + u32 bitonic + outputs + tie flags ============
__global__ __launch_bounds__(512)
void lcm_kernel(const float* __restrict__ x, const float* __restrict__ c,
                float* __restrict__ out, unsigned* __restrict__ flags) {
#pragma clang fp contract(off)
  __shared__ unsigned keys[RPB * NU];   // 16 KB
  __shared__ float ztab[9];

  const int t = threadIdx.x;
  const int r0 = blockIdx.x * RPB;

  if (t < 9) ztab[t] = (t < 8) ? (1.0f / (float)(t + 1)) : 0.0f;

  // ---- distances: XLA-CPU AVX-512-style reduce, bitwise identical to r6 ----
  {
    const int n = t;
    float4 cs4[16];
    const float4* c4 = (const float4*)c + (size_t)n * 16;
#pragma unroll
    for (int q = 0; q < 16; ++q) cs4[q] = c4[q];

    float* o_d = out;
#pragma unroll
    for (int r = 0; r < RPB; ++r) {
      const float* __restrict__ xr = x + (size_t)(r0 + r) * FEATS;  // uniform
      float rr[16];
#pragma unroll
      for (int k = 0; k < 4; ++k) {
        const float4 xq0 = *(const float4*)(xr + 16 * k + 0);
        const float4 xq1 = *(const float4*)(xr + 16 * k + 4);
        const float4 xq2 = *(const float4*)(xr + 16 * k + 8);
        const float4 xq3 = *(const float4*)(xr + 16 * k + 12);
        const float4 xq[4] = {xq0, xq1, xq2, xq3};
#pragma unroll
        for (int q = 0; q < 4; ++q) {
          const float4 cv = cs4[k * 4 + q];
          const float4 xv = xq[q];
          const float t0 = xv.x - cv.x;
          const float t1 = xv.y - cv.y;
          const float t2 = xv.z - cv.z;
          const float t3 = xv.w - cv.w;
          if (k == 0) {
            rr[q * 4 + 0] = t0 * t0; rr[q * 4 + 1] = t1 * t1;
            rr[q * 4 + 2] = t2 * t2; rr[q * 4 + 3] = t3 * t3;
          } else {
            rr[q * 4 + 0] = rr[q * 4 + 0] + t0 * t0;
            rr[q * 4 + 1] = rr[q * 4 + 1] + t1 * t1;
            rr[q * 4 + 2] = rr[q * 4 + 2] + t2 * t2;
            rr[q * 4 + 3] = rr[q * 4 + 3] + t3 * t3;
          }
        }
      }
      float s8[8], s4[4], s2[2];
#pragma unroll
      for (int j = 0; j < 8; ++j) s8[j] = rr[j] + rr[j + 8];
#pragma unroll
      for (int j = 0; j < 4; ++j) s4[j] = s8[j] + s8[j + 4];
#pragma unroll
      for (int j = 0; j < 2; ++j) s2[j] = s4[j] + s4[j + 2];
      const float tot = s2[0] + s2[1];
      const float dv = (float)__builtin_sqrt((double)tot);
      o_d[(size_t)(r0 + r) * NU + n] = dv;

      // 32-bit key: d in [4,16) -> 24-bit offset; drop 1 bit; | idx(9b).
      // Out-of-range clamps are monotone (single OOR is still correctly
      // ordered); multi-OOR / dropped-bit ambiguity ties -> row flagged.
      const unsigned db = __float_as_uint(dv);
      unsigned q;
      if (db < 0x40800000u) q = 0u;
      else {
        const unsigned off = db - 0x40800000u;
        q = off > 0x00FFFFFFu ? 0x00FFFFFFu : off;
      }
      q >>= 1;
      keys[r * NU + n] = (q << 9) | (unsigned)n;
    }
  }
  __syncthreads();

  // ---- per-wave bitonic sort of 512 u32 keys (wave w = row w) ----
  {
    const unsigned lane = (unsigned)(t & 63);
    const int w = t >> 6;

    unsigned v[8];
#pragma unroll
    for (int i = 0; i < 8; ++i) v[i] = keys[w * NU + i * 64 + (int)lane];

    // pre-stages K=2,4,8
    ce32(v[0], v[1], true);  ce32(v[2], v[3], false);
    ce32(v[4], v[5], true);  ce32(v[6], v[7], false);
    ce32(v[0], v[2], true);  ce32(v[1], v[3], true);
    ce32(v[4], v[6], false); ce32(v[5], v[7], false);
    ce32(v[0], v[1], true);  ce32(v[2], v[3], true);
    ce32(v[4], v[5], false); ce32(v[6], v[7], false);
    {
      const bool a8 = ((lane & 1u) == 0u);
      ce32(v[0], v[4], a8); ce32(v[1], v[5], a8); ce32(v[2], v[6], a8); ce32(v[3], v[7], a8);
      ce32(v[0], v[2], a8); ce32(v[1], v[3], a8); ce32(v[4], v[6], a8); ce32(v[5], v[7], a8);
      ce32(v[0], v[1], a8); ce32(v[2], v[3], a8); ce32(v[4], v[5], a8); ce32(v[6], v[7], a8);
    }
    const int ad4  = (int)((lane ^ 4u)  << 2);
    const int ad8  = (int)((lane ^ 8u)  << 2);
    const int ad16 = (int)((lane ^ 16u) << 2);
    const int ad32 = (int)((lane ^ 32u) << 2);
    stage32<16>(v, lane, ad4, ad8, ad16, ad32);
    stage32<32>(v, lane, ad4, ad8, ad16, ad32);
    stage32<64>(v, lane, ad4, ad8, ad16, ad32);
    stage32<128>(v, lane, ad4, ad8, ad16, ad32);
    stage32<256>(v, lane, ad4, ad8, ad16, ad32);
    stage32<512>(v, lane, ad4, ad8, ad16, ad32);

    const int row = r0 + w;
    float* o_is = out + (size_t)B_ROWS * NU;
    float* o_k  = o_is + (size_t)B_ROWS * NU;
    float* o_z  = o_k + (size_t)B_ROWS * NU;
    float* o_xc = o_z + (size_t)B_ROWS * NU;

    int idxv[8];
#pragma unroll
    for (int i = 0; i < 8; ++i) idxv[i] = (int)(v[i] & 0x1ffu);

    // i_sort: coalesced float4 x2
    float4 fa, fb;
    fa.x = (float)idxv[0]; fa.y = (float)idxv[1];
    fa.z = (float)idxv[2]; fa.w = (float)idxv[3];
    fb.x = (float)idxv[4]; fb.y = (float)idxv[5];
    fb.z = (float)idxv[6]; fb.w = (float)idxv[7];
    float4* isrow = (float4*)(o_is + (size_t)row * NU);
    isrow[lane * 2 + 0] = fa;
    isrow[lane * 2 + 1] = fb;

    // rank scatter into LDS (reuse this wave's keys row), then coalesced k/z
    unsigned* krow = keys + w * NU;
#pragma unroll
    for (int i = 0; i < 8; ++i) krow[idxv[i]] = (unsigned)(lane * 8 + i);
    asm volatile("s_waitcnt lgkmcnt(0)" ::: "memory");
    const uint4 ka = ((const uint4*)krow)[lane * 2 + 0];
    const uint4 kb = ((const uint4*)krow)[lane * 2 + 1];

    float4 k0, k1;
    k0.x = (float)ka.x; k0.y = (float)ka.y; k0.z = (float)ka.z; k0.w = (float)ka.w;
    k1.x = (float)kb.x; k1.y = (float)kb.y; k1.z = (float)kb.z; k1.w = (float)kb.w;
    float4* krow_g = (float4*)(o_k + (size_t)row * NU);
    krow_g[lane * 2 + 0] = k0;
    krow_g[lane * 2 + 1] = k1;

    float4 z0, z1;
    z0.x = ztab[ka.x < 8u ? ka.x : 8u]; z0.y = ztab[ka.y < 8u ? ka.y : 8u];
    z0.z = ztab[ka.z < 8u ? ka.z : 8u]; z0.w = ztab[ka.w < 8u ? ka.w : 8u];
    z1.x = ztab[kb.x < 8u ? kb.x : 8u]; z1.y = ztab[kb.y < 8u ? kb.y : 8u];
    z1.z = ztab[kb.z < 8u ? kb.z : 8u]; z1.w = ztab[kb.w < 8u ? kb.w : 8u];
    float4* zrow_g = (float4*)(o_z + (size_t)row * NU);
    zrow_g[lane * 2 + 0] = z0;
    zrow_g[lane * 2 + 1] = z1;

    int top = idxv[0];
    top = __shfl(top, 0, 64);
    o_xc[(size_t)row * FEATS + (int)lane] = c[top * FEATS + (int)lane];

    // flag rows with ambiguous quantized order
    bool tie = false;
#pragma unroll
    for (int i = 0; i < 7; ++i) tie |= ((v[i] >> 9) == (v[i + 1] >> 9));
    const unsigned q0 = v[0] >> 9;
    const unsigned q7 = v[7] >> 9;
    const unsigned nq0 = (unsigned)__shfl_down((int)q0, 1, 64);
    if (lane < 63) tie |= (q7 == nq0);
    const ull tb = __ballot(tie);
    if (lane == 0) flags[row] = (tb != 0ULL) ? 1u : 0u;
  }
}

// ============ kernel 2: exact u64 stable re-sort for flagged rows ============
__global__ __launch_bounds__(64)
void fix_kernel(const float* __restrict__ c, float* __restrict__ out,
                const unsigned* __restrict__ flags) {
  const int row = blockIdx.x;
  if (flags[row] == 0u) return;
  const unsigned lane = threadIdx.x;

  const float* drow = out + (size_t)row * NU;
  ull v[8];
#pragma unroll
  for (int i = 0; i < 8; ++i) {
    const float dv = drow[i * 64 + (int)lane];
    v[i] = ((ull)__float_as_uint(dv) << 32) | (ull)(unsigned)(i * 64 + (int)lane);
  }

  inreg_pass<1>(v, lane, 2u);
  inreg_pass<2>(v, lane, 4u);
  inreg_pass<1>(v, lane, 4u);
  inreg_pass<4>(v, lane, 8u);
  inreg_pass<2>(v, lane, 8u);
  inreg_pass<1>(v, lane, 8u);
  for (unsigned k = 16; k <= 512; k <<= 1) {
    for (unsigned j = k >> 1; j >= 8; j >>= 1) cross_pass(v, lane, j >> 3, k);
    inreg_pass<4>(v, lane, k);
    inreg_pass<2>(v, lane, k);
    inreg_pass<1>(v, lane, k);
  }

  float* o_is = out + (size_t)B_ROWS * NU;
  float* o_k  = o_is + (size_t)B_ROWS * NU;
  float* o_z  = o_k + (size_t)B_ROWS * NU;
  float* o_xc = o_z + (size_t)B_ROWS * NU;

  int idxv[8];
#pragma unroll
  for (int i = 0; i < 8; ++i) idxv[i] = (int)(v[i] & 0x1ffULL);

  float4 fa, fb;
  fa.x = (float)idxv[0]; fa.y = (float)idxv[1];
  fa.z = (float)idxv[2]; fa.w = (float)idxv[3];
  fb.x = (float)idxv[4]; fb.y = (float)idxv[5];
  fb.z = (float)idxv[6]; fb.w = (float)idxv[7];
  float4* isrow = (float4*)(o_is + (size_t)row * NU);
  isrow[lane * 2 + 0] = fa;
  isrow[lane * 2 + 1] = fb;

#pragma unroll
  for (int i = 0; i < 8; ++i) {
    const int e = (int)lane * 8 + i;
    o_k[(size_t)row * NU + idxv[i]] = (float)e;
    o_z[(size_t)row * NU + idxv[i]] = (e < TOPK_K) ? (1.0f / (float)(i + 1)) : 0.0f;
  }

  int top = idxv[0];
  top = __shfl(top, 0, 64);
  o_xc[(size_t)row * FEATS + (int)lane] = c[top * FEATS + (int)lane];
}

extern "C" void kernel_launch(void* const* d_in, const int* in_sizes, int n_in,
                              void* d_out, int out_size, void* d_ws, size_t ws_size,
                              hipStream_t stream) {
  const float* x = (const float*)d_in[0];
  const float* c = (const float*)d_in[1];
  float* out = (float*)d_out;
  unsigned* flags = (unsigned*)d_ws;
  lcm_kernel<<<dim3(B_ROWS / RPB), dim3(512), 0, stream>>>(x, c, out, flags);
  fix_kernel<<<dim3(B_ROWS), dim3(64), 0, stream>>>(c, out, flags);
}